// Round 3
// baseline (360.592 us; speedup 1.0000x reference)
//
#include <hip/hip_runtime.h>

#define NY 512
#define NX 512
#define CC 64
#define NYNX (NY * NX)   // 262144 = 2^18

// ---------------- gather path (primary) ----------------

__global__ __launch_bounds__(256) void init_map_kernel(int4* __restrict__ map4, int n4) {
    int i = blockIdx.x * blockDim.x + threadIdx.x;
    if (i < n4) map4[i] = make_int4(-1, -1, -1, -1);
}

__global__ __launch_bounds__(256) void build_map_kernel(const int4* __restrict__ coords,
                                                        int* __restrict__ map, int P) {
    int p = blockIdx.x * blockDim.x + threadIdx.x;
    if (p < P) {
        int4 c = coords[p];                      // (b, z, y, x)
        int flat = c.x * NYNX + c.z * NX + c.w;  // b*NY*NX + y*NX + x
        map[flat] = p;
    }
}

__global__ __launch_bounds__(256) void gather_kernel(const float4* __restrict__ feat4,
                                                     const int* __restrict__ map,
                                                     float* __restrict__ out, int ncells) {
    int f = blockIdx.x * blockDim.x + threadIdx.x;  // flat cell index in [0, B*NY*NX)
    if (f >= ncells) return;
    int b = f >> 18;              // f / NYNX
    int r = f & (NYNX - 1);       // y*NX + x
    int p = map[f];
    int ps = p < 0 ? 0 : p;       // safe index; empty lanes load point 0 (L2-cached broadcast)

    const float4* src = feat4 + (size_t)ps * (CC / 4);
    float4 v[16];
#pragma unroll
    for (int j = 0; j < 16; ++j) v[j] = src[j];   // 16 independent 16B loads: full MLP
    if (p < 0) {
#pragma unroll
        for (int j = 0; j < 16; ++j) v[j] = make_float4(0.f, 0.f, 0.f, 0.f);
    }

    // out[b][c][y][x] = out[(b*CC + c)*NYNX + r]; consecutive lanes -> consecutive r
    float* o = out + (size_t)b * (size_t)CC * (size_t)NYNX + (size_t)r;
#pragma unroll
    for (int j = 0; j < 16; ++j) {
        o[(size_t)(4 * j + 0) * NYNX] = v[j].x;
        o[(size_t)(4 * j + 1) * NYNX] = v[j].y;
        o[(size_t)(4 * j + 2) * NYNX] = v[j].z;
        o[(size_t)(4 * j + 3) * NYNX] = v[j].w;
    }
}

// ---------------- fallback path (only if ws too small) ----------------

__global__ __launch_bounds__(256) void zero_kernel(float4* __restrict__ out4, int n4) {
    int i = blockIdx.x * blockDim.x + threadIdx.x;
    if (i < n4) out4[i] = make_float4(0.f, 0.f, 0.f, 0.f);
}

__global__ __launch_bounds__(256) void scatter_kernel(const float* __restrict__ feat,
                                                      const int4* __restrict__ coords,
                                                      float* __restrict__ out, int P) {
    int idx = blockIdx.x * blockDim.x + threadIdx.x;  // p*64 + c
    int p = idx >> 6;
    int c = idx & 63;
    if (p < P) {
        int4 co = coords[p];
        out[((size_t)(co.x * CC + c)) * NYNX + (size_t)(co.z * NX + co.w)] = feat[idx];
    }
}

extern "C" void kernel_launch(void* const* d_in, const int* in_sizes, int n_in,
                              void* d_out, int out_size, void* d_ws, size_t ws_size,
                              hipStream_t stream) {
    const float* feat = (const float*)d_in[0];
    const int* coords = (const int*)d_in[1];
    int P = in_sizes[0] / CC;          // 400000
    int ncells = out_size / CC;        // B * NY * NX
    float* out = (float*)d_out;

    if (ws_size >= (size_t)ncells * sizeof(int)) {
        int* map = (int*)d_ws;
        int n4 = ncells / 4;
        init_map_kernel<<<(n4 + 255) / 256, 256, 0, stream>>>((int4*)map, n4);
        build_map_kernel<<<(P + 255) / 256, 256, 0, stream>>>((const int4*)coords, map, P);
        gather_kernel<<<(ncells + 255) / 256, 256, 0, stream>>>((const float4*)feat, map, out, ncells);
    } else {
        int n4 = out_size / 4;
        zero_kernel<<<(n4 + 255) / 256, 256, 0, stream>>>((float4*)out, n4);
        scatter_kernel<<<(P * CC + 255) / 256, 256, 0, stream>>>(feat, (const int4*)coords, out, P);
    }
}